// Round 4
// baseline (298.242 us; speedup 1.0000x reference)
//
#include <hip/hip_runtime.h>
#include <hip/hip_bf16.h>
#include <stdint.h>

typedef __bf16 bf16x8 __attribute__((ext_vector_type(8)));
typedef float  f32x4  __attribute__((ext_vector_type(4)));
using bf16 = __hip_bfloat16;

#define NNODES 8192
#define FIN    8256      // 8192 + 64
#define NCOL   192       // 128 (W1) + 64 (W2 top)
#define KTILES 129       // 8256 / 64
#define BM     64

// ---- workspace layout (bytes) ----
enum : size_t {
  WCT_OFF  = 0,            // bf16 [192][8256]   3,170,304
  CNT_OFF  = 3170304,      // int  [8192]
  OFF_OFF  = 3203072,      // int  [8193]
  CUR_OFF  = 3236096,      // int  [8192]
  DNV_OFF  = 3268864,      // f32  [8192]
  CSR_OFF  = 3301632,      // int  [262144]
  H1_OFF   = 4350208,      // bf16 [8192][128]   (2 MB used of 4.2 MB slot)
  HX2_OFF  = 8544512,      // f32  [8192][64]
  RU_OFF   = 10641664,     // f32  [8192][128]
  H2_OFF   = 14835968,     // bf16 [8192][64]    (1 MB used)
  YP_OFF   = 16933120,     // f32  [ksplit][8192][192]
  YP_SLICE = 6291456
};

__device__ __forceinline__ void barrier_lgkm() {
  asm volatile("s_waitcnt lgkmcnt(0)" ::: "memory");
  __builtin_amdgcn_s_barrier();
  asm volatile("" ::: "memory");
}

__global__ void k_zero_i(int* p, int n) {
  int i = blockIdx.x * 256 + threadIdx.x;
  if (i < n) p[i] = 0;
}

__global__ void k_out_zero(float* out) {
  int i = blockIdx.x * 256 + threadIdx.x;
  if (i < NNODES * 64) out[i] = 0.f;   // diagnostic signature if ws too small
}

// LDS-tiled transpose+convert: wct[c][k] = bf16( c<128 ? W1[k][c] : (k<8192 ? W2[k][c-128] : 0) )
__global__ void k_prep_wct(const float* __restrict__ W1, const float* __restrict__ W2,
                           bf16* __restrict__ wct) {
  __shared__ bf16 tile[32][33];
  const int kt = blockIdx.x * 32, ct = blockIdx.y * 32;
  const int tx = threadIdx.x & 31, ty = threadIdx.x >> 5;
#pragma unroll
  for (int r = 0; r < 4; ++r) {
    int k = kt + ty + r * 8, c = ct + tx;
    float v = 0.f;
    if (c < 128)       v = W1[(size_t)k * 128 + c];
    else if (k < 8192) v = W2[(size_t)k * 64 + (c - 128)];
    tile[ty + r * 8][tx] = __float2bfloat16(v);
  }
  __syncthreads();
#pragma unroll
  for (int r = 0; r < 4; ++r) {
    int c = ct + ty + r * 8;
    wct[(size_t)c * FIN + kt + tx] = tile[tx][ty + r * 8];
  }
}

__global__ void k_hist(const int* __restrict__ ei, int E, int* cnt) {
  int e = blockIdx.x * 256 + threadIdx.x;
  if (e < E) atomicAdd(&cnt[ei[E + e]], 1);
}

__global__ void k_scan(const int* __restrict__ cnt, int* __restrict__ offs,
                       int* __restrict__ cur, float* __restrict__ dinv) {
  __shared__ int part[256];
  int tid = threadIdx.x;
  int base = tid * 32;
  int s = 0;
#pragma unroll
  for (int j = 0; j < 32; j++) s += cnt[base + j];
  part[tid] = s;
  __syncthreads();
  for (int off = 1; off < 256; off <<= 1) {
    int a = (tid >= off) ? part[tid - off] : 0;
    __syncthreads();
    part[tid] += a;
    __syncthreads();
  }
  int run = (tid == 0) ? 0 : part[tid - 1];
  for (int j = 0; j < 32; j++) {
    int c = cnt[base + j];
    offs[base + j] = run;
    cur[base + j]  = run;
    dinv[base + j] = rsqrtf((float)(c + 1));
    run += c;
  }
  if (tid == 255) offs[NNODES] = run;
}

__global__ void k_fill(const int* __restrict__ ei, int E, int* cur, int* __restrict__ csr) {
  int e = blockIdx.x * 256 + threadIdx.x;
  if (e < E) {
    int d = ei[E + e];
    int p = atomicAdd(&cur[d], 1);
    csr[p] = ei[e];
  }
}

__device__ __forceinline__ bf16x8 pack8(float4 a, float4 b) {
  union { bf16 h[8]; bf16x8 v; } u;
  u.h[0] = __float2bfloat16(a.x); u.h[1] = __float2bfloat16(a.y);
  u.h[2] = __float2bfloat16(a.z); u.h[3] = __float2bfloat16(a.w);
  u.h[4] = __float2bfloat16(b.x); u.h[5] = __float2bfloat16(b.y);
  u.h[6] = __float2bfloat16(b.z); u.h[7] = __float2bfloat16(b.w);
  return u.v;
}

__device__ __forceinline__ void loadA(const float* __restrict__ ax,
                                      const float* __restrict__ ah,
                                      int k0, float4* av) {
  const float* p = (k0 < 8192) ? (ax + k0) : (ah + (k0 - 8192));
  av[0] = ((const float4*)p)[0];
  av[1] = ((const float4*)p)[1];
  av[2] = ((const float4*)(p + 32))[0];
  av[3] = ((const float4*)(p + 32))[1];
}

// C = [x | hidden] @ [W1 | W2top] : M=8192, N=192, K=8256
// grid (128, ksplit), 256 threads = 4 waves (wave w owns rows w*16..w*16+15, all 192 cols).
// A: direct global->reg with in-reg fp32->bf16 cvt, 1-tile register prefetch.
// B: LDS double-buffer (XOR slot swizzle, same expr both sides), raw barriers, vmcnt never drained.
__global__ __launch_bounds__(256, 2) void k_gemm(const float* __restrict__ x,
                                                 const float* __restrict__ hid,
                                                 const bf16* __restrict__ wct,
                                                 float* __restrict__ yp,
                                                 bf16* __restrict__ h1d,
                                                 float* __restrict__ hx2d,
                                                 int tpc) {
  __shared__ uint4 smB[2][192][8];   // 2 x 24 KB
  const int tid = threadIdx.x;
  const int lane = tid & 63, w = tid >> 6;
  const int rl = lane & 15, g = lane >> 4;
  const int m0 = blockIdx.x * BM;
  const int row = m0 + w * 16 + rl;
  const int chunk = blockIdx.y;
  const int t_lo = chunk * tpc;
  const int t_hi = (t_lo + tpc > KTILES) ? KTILES : (t_lo + tpc);
  const int nt = t_hi - t_lo;

  // A per-lane bases (row fixed, k varies)
  const float* ax = x + (size_t)row * 8192 + g * 8;
  const float* ah = hid + (size_t)row * 64 + g * 8;

  // B staging: 1536 16B units, 6 per thread
  const bf16* pb[6];
  int bc[6], bt[6];
#pragma unroll
  for (int q = 0; q < 6; ++q) {
    int u = tid + q * 256;
    bc[q] = u >> 3; bt[q] = u & 7;
    pb[q] = wct + (size_t)bc[q] * FIN + bt[q] * 8;
  }

  f32x4 acc[12] = {};
  float4 avc[4], avn[4];
  uint4 bvn[6];

  // prologue: A(t0), B(t0) -> LDS[0]; B(t0+1) -> regs
  loadA(ax, ah, t_lo * 64, avc);
#pragma unroll
  for (int q = 0; q < 6; ++q) bvn[q] = *(const uint4*)(pb[q] + t_lo * 64);
#pragma unroll
  for (int q = 0; q < 6; ++q) smB[0][bc[q]][bt[q] ^ (bc[q] & 7)] = bvn[q];
  if (nt > 1) {
#pragma unroll
    for (int q = 0; q < 6; ++q) bvn[q] = *(const uint4*)(pb[q] + (t_lo + 1) * 64);
  }
  barrier_lgkm();

  const int sw = g ^ (rl & 7);
  for (int it = 0; it < nt; ++it) {
    const int c = it & 1;
    const bool hn = (it + 1 < nt);
    if (hn) loadA(ax, ah, (t_lo + it + 1) * 64, avn);

    const uint4* bbase = &smB[c][0][0];
#pragma unroll
    for (int kk = 0; kk < 2; ++kk) {
      bf16x8 afrag = pack8(avc[kk * 2], avc[kk * 2 + 1]);
      const uint4* bk = bbase + rl * 8 + (sw ^ (kk * 4));
#pragma unroll
      for (int nf = 0; nf < 12; ++nf) {
        bf16x8 bfrag = *(const bf16x8*)(bk + nf * 128);
        acc[nf] = __builtin_amdgcn_mfma_f32_16x16x32_bf16(afrag, bfrag, acc[nf], 0, 0, 0);
      }
    }
    barrier_lgkm();                     // b1: all waves done reading LDS[c^1] (last iter)
    if (hn) {
#pragma unroll
      for (int q = 0; q < 6; ++q) smB[c ^ 1][bc[q]][bt[q] ^ (bc[q] & 7)] = bvn[q];
      if (it + 2 < nt) {
#pragma unroll
        for (int q = 0; q < 6; ++q) bvn[q] = *(const uint4*)(pb[q] + (t_lo + it + 2) * 64);
      }
#pragma unroll
      for (int q = 0; q < 4; ++q) avc[q] = avn[q];
    }
    barrier_lgkm();                     // b2: B(t+1) writes visible
  }

  // C/D layout (HW-verified): col = lane&15, row = (lane>>4)*4 + reg
  if (h1d) {  // direct mode (ksplit==1)
#pragma unroll
    for (int nf = 0; nf < 12; ++nf) {
      int col = nf * 16 + rl;
#pragma unroll
      for (int tt = 0; tt < 4; ++tt) {
        int r = m0 + w * 16 + g * 4 + tt;
        float vv = acc[nf][tt];
        if (col < 128) h1d[(size_t)r * 128 + col] = __float2bfloat16(vv);
        else           hx2d[(size_t)r * 64 + (col - 128)] = vv;
      }
    }
  } else {
    float* ypc = yp + (size_t)chunk * ((size_t)NNODES * NCOL);
#pragma unroll
    for (int nf = 0; nf < 12; ++nf) {
      int col = nf * 16 + rl;
#pragma unroll
      for (int tt = 0; tt < 4; ++tt) {
        int r = m0 + w * 16 + g * 4 + tt;
        ypc[(size_t)r * NCOL + col] = acc[nf][tt];
      }
    }
  }
}

// sum K-split partials; h1 -> bf16, hx2 -> fp32
__global__ void k_reduce(const float* __restrict__ yp, bf16* __restrict__ h1,
                         float* __restrict__ hx2, int nch) {
  int idx = blockIdx.x * 256 + threadIdx.x;  // < 8192*192
  float s = 0.f;
  for (int c = 0; c < nch; c++) s += yp[(size_t)c * ((size_t)NNODES * NCOL) + idx];
  int i = idx / NCOL, c = idx - i * NCOL;
  if (c < 128) h1[(size_t)i * 128 + c] = __float2bfloat16(s);
  else         hx2[(size_t)i * 64 + (c - 128)] = s;
}

__device__ __forceinline__ float bflo(unsigned v) { return __uint_as_float(v << 16); }
__device__ __forceinline__ float bfhi(unsigned v) { return __uint_as_float(v & 0xffff0000u); }

// one wave per node: ru = sigmoid(selfloop + sum_edges h1[src]*dinv[src]*dinv[dst] + b1)
__global__ void k_scat1(const bf16* __restrict__ h1b, const int* __restrict__ offs,
                        const int* __restrict__ csr, const float* __restrict__ dinv,
                        const float* __restrict__ b1, float* __restrict__ ru) {
  int node = blockIdx.x * 4 + (threadIdx.x >> 6);
  int lane = threadIdx.x & 63;
  const unsigned* h1u = (const unsigned*)h1b;   // 64 uints per row
  float dd = dinv[node];
  unsigned vv = h1u[(size_t)node * 64 + lane];
  float ax = bflo(vv) * dd * dd, ay = bfhi(vv) * dd * dd;
  int e0 = offs[node], e1 = offs[node + 1];
  for (int e = e0; e < e1; ++e) {
    int s = csr[e];
    float nrm = dinv[s] * dd;
    unsigned wv = h1u[(size_t)s * 64 + lane];
    ax += bflo(wv) * nrm;
    ay += bfhi(wv) * nrm;
  }
  ax += b1[lane * 2];
  ay += b1[lane * 2 + 1];
  ax = 1.f / (1.f + expf(-ax));
  ay = 1.f / (1.f + expf(-ay));
  ru[(size_t)node * 128 + lane * 2]     = ax;
  ru[(size_t)node * 128 + lane * 2 + 1] = ay;
}

// h2[i] = hx2[i] + (r[i] .* hidden[i]) @ W2_bottom  (r via the flat-reshape quirk)
__global__ void k_rh(const float* __restrict__ ru, const float* __restrict__ hidden,
                     const float* __restrict__ hx2, const float* __restrict__ W2,
                     bf16* __restrict__ h2) {
  __shared__ float W2s[64][64];
  __shared__ float rhs[4][64];
  int tid = threadIdx.x;
#pragma unroll
  for (int t = 0; t < 16; ++t) {
    int idx = tid + 256 * t;  // 4096
    int j = idx >> 6, c = idx & 63;
    W2s[j][c] = W2[(size_t)(8192 + j) * 64 + c];
  }
  int w = tid >> 6, lane = tid & 63;
  int i = blockIdx.x * 4 + w;
  float rv = ru[(size_t)(i >> 1) * 128 + ((i & 1) << 6) + lane];
  float hv = hidden[(size_t)i * 64 + lane];
  rhs[w][lane] = rv * hv;
  __syncthreads();
  float acc = hx2[(size_t)i * 64 + lane];
#pragma unroll 8
  for (int j = 0; j < 64; ++j) acc += rhs[w][j] * W2s[j][lane];
  h2[(size_t)i * 64 + lane] = __float2bfloat16(acc);
}

// one wave per node: c = tanh(gather(h2)+b2); out = u*h + (1-u)*c  (u via reshape quirk)
__global__ void k_scat2(const bf16* __restrict__ h2b, const int* __restrict__ offs,
                        const int* __restrict__ csr, const float* __restrict__ dinv,
                        const float* __restrict__ b2, const float* __restrict__ ru,
                        const float* __restrict__ hidden, float* __restrict__ out) {
  int node = blockIdx.x * 4 + (threadIdx.x >> 6);
  int lane = threadIdx.x & 63;
  const unsigned short* h2u = (const unsigned short*)h2b;
  float dd = dinv[node];
  float acc = bflo((unsigned)h2u[(size_t)node * 64 + lane]) * dd * dd;
  int e0 = offs[node], e1 = offs[node + 1];
  for (int e = e0; e < e1; ++e) {
    int s = csr[e];
    acc += bflo((unsigned)h2u[(size_t)s * 64 + lane]) * dinv[s] * dd;
  }
  acc += b2[lane];
  float cv = tanhf(acc);
  float u = ru[(size_t)(4096 + (node >> 1)) * 128 + ((node & 1) << 6) + lane];
  float hv = hidden[(size_t)node * 64 + lane];
  out[(size_t)node * 64 + lane] = u * hv + (1.f - u) * cv;
}

extern "C" void kernel_launch(void* const* d_in, const int* in_sizes, int n_in,
                              void* d_out, int out_size, void* d_ws, size_t ws_size,
                              hipStream_t stream) {
  (void)n_in; (void)out_size;
  const float* x   = (const float*)d_in[0];
  const float* hid = (const float*)d_in[1];
  const float* W1  = (const float*)d_in[2];
  const float* b1  = (const float*)d_in[3];
  const float* W2  = (const float*)d_in[4];
  const float* b2  = (const float*)d_in[5];
  const int*   ei  = (const int*)d_in[6];
  const int E = in_sizes[6] / 2;
  float* out = (float*)d_out;

  int ksplit;
  if      (ws_size >= YP_OFF + 8ull * YP_SLICE) ksplit = 8;
  else if (ws_size >= YP_OFF + 4ull * YP_SLICE) ksplit = 4;
  else if (ws_size >= YP_OFF + 2ull * YP_SLICE) ksplit = 2;
  else if (ws_size >= YP_OFF)                   ksplit = 1;   // direct mode
  else {
    k_out_zero<<<dim3(NNODES * 64 / 256), dim3(256), 0, stream>>>(out);
    return;
  }
  const int tpc = (KTILES + ksplit - 1) / ksplit;

  char* ws = (char*)d_ws;
  bf16*  wct  = (bf16*)(ws + WCT_OFF);
  int*   cnt  = (int*)(ws + CNT_OFF);
  int*   offs = (int*)(ws + OFF_OFF);
  int*   cur  = (int*)(ws + CUR_OFF);
  float* dinv = (float*)(ws + DNV_OFF);
  int*   csr  = (int*)(ws + CSR_OFF);
  bf16*  h1   = (bf16*)(ws + H1_OFF);
  float* hx2  = (float*)(ws + HX2_OFF);
  float* ru   = (float*)(ws + RU_OFF);
  bf16*  h2   = (bf16*)(ws + H2_OFF);
  float* yp   = (float*)(ws + YP_OFF);

  k_zero_i<<<dim3(32), dim3(256), 0, stream>>>(cnt, NNODES);
  k_prep_wct<<<dim3(FIN / 32, NCOL / 32), dim3(256), 0, stream>>>(W1, W2, wct);
  k_hist<<<dim3((E + 255) / 256), dim3(256), 0, stream>>>(ei, E, cnt);
  k_scan<<<dim3(1), dim3(256), 0, stream>>>(cnt, offs, cur, dinv);
  k_fill<<<dim3((E + 255) / 256), dim3(256), 0, stream>>>(ei, E, cur, csr);
  if (ksplit == 1) {
    k_gemm<<<dim3(NNODES / BM, 1), dim3(256), 0, stream>>>(x, hid, wct, nullptr, h1, hx2, tpc);
  } else {
    k_gemm<<<dim3(NNODES / BM, ksplit), dim3(256), 0, stream>>>(x, hid, wct, yp, nullptr, nullptr, tpc);
    k_reduce<<<dim3(NNODES * NCOL / 256), dim3(256), 0, stream>>>(yp, h1, hx2, ksplit);
  }
  k_scat1<<<dim3(NNODES / 4), dim3(256), 0, stream>>>(h1, offs, csr, dinv, b1, ru);
  k_rh<<<dim3(NNODES / 4), dim3(256), 0, stream>>>(ru, hid, hx2, W2, h2);
  k_scat2<<<dim3(NNODES / 4), dim3(256), 0, stream>>>(h2, offs, csr, dinv, b2, ru, hid, out);
}

// Round 5
// 263.857 us; speedup vs baseline: 1.1303x; 1.1303x over previous
//
#include <hip/hip_runtime.h>
#include <hip/hip_bf16.h>
#include <stdint.h>

typedef __bf16 bf16x8 __attribute__((ext_vector_type(8)));
typedef float  f32x4  __attribute__((ext_vector_type(4)));
using bf16 = __hip_bfloat16;

#define NNODES 8192
#define FIN    8256      // 8192 + 64
#define NCOL   192       // 128 (W1) + 64 (W2 top)
#define KT32   258       // 8256 / 32
#define BMB    128       // rows per block (4 waves x 32 rows)

// ---- workspace layout (bytes) ----
enum : size_t {
  WCT_OFF  = 0,            // bf16 [192][8256]   3,170,304
  CNT_OFF  = 3170304,      // int  [8192]
  OFF_OFF  = 3203072,      // int  [8193]
  CUR_OFF  = 3236096,      // int  [8192]
  DNV_OFF  = 3268864,      // f32  [8192]
  CSR_OFF  = 3301632,      // int  [262144]
  H1_OFF   = 4350208,      // bf16 [8192][128]
  HX2_OFF  = 8544512,      // f32  [8192][64]
  RU_OFF   = 10641664,     // f32  [8192][128]
  H2_OFF   = 14835968,     // bf16 [8192][64]
  YP_OFF   = 16933120,     // f32  [ksplit][8192][192]
  YP_SLICE = 6291456
};

__global__ void k_zero_i(int* p, int n) {
  int i = blockIdx.x * 256 + threadIdx.x;
  if (i < n) p[i] = 0;
}

__global__ void k_out_zero(float* out) {
  int i = blockIdx.x * 256 + threadIdx.x;
  if (i < NNODES * 64) out[i] = 0.f;   // diagnostic signature if ws too small
}

// LDS-tiled transpose+convert: wct[c][k] = bf16( c<128 ? W1[k][c] : (k<8192 ? W2[k][c-128] : 0) )
__global__ void k_prep_wct(const float* __restrict__ W1, const float* __restrict__ W2,
                           bf16* __restrict__ wct) {
  __shared__ bf16 tile[32][33];
  const int kt = blockIdx.x * 32, ct = blockIdx.y * 32;
  const int tx = threadIdx.x & 31, ty = threadIdx.x >> 5;
#pragma unroll
  for (int r = 0; r < 4; ++r) {
    int k = kt + ty + r * 8, c = ct + tx;
    float v = 0.f;
    if (c < 128)       v = W1[(size_t)k * 128 + c];
    else if (k < 8192) v = W2[(size_t)k * 64 + (c - 128)];
    tile[ty + r * 8][tx] = __float2bfloat16(v);
  }
  __syncthreads();
#pragma unroll
  for (int r = 0; r < 4; ++r) {
    int c = ct + ty + r * 8;
    wct[(size_t)c * FIN + kt + tx] = tile[tx][ty + r * 8];
  }
}

__global__ void k_hist(const int* __restrict__ ei, int E, int* cnt) {
  int e = blockIdx.x * 256 + threadIdx.x;
  if (e < E) atomicAdd(&cnt[ei[E + e]], 1);
}

__global__ void k_scan(const int* __restrict__ cnt, int* __restrict__ offs,
                       int* __restrict__ cur, float* __restrict__ dinv) {
  __shared__ int part[256];
  int tid = threadIdx.x;
  int base = tid * 32;
  int s = 0;
#pragma unroll
  for (int j = 0; j < 32; j++) s += cnt[base + j];
  part[tid] = s;
  __syncthreads();
  for (int off = 1; off < 256; off <<= 1) {
    int a = (tid >= off) ? part[tid - off] : 0;
    __syncthreads();
    part[tid] += a;
    __syncthreads();
  }
  int run = (tid == 0) ? 0 : part[tid - 1];
  for (int j = 0; j < 32; j++) {
    int c = cnt[base + j];
    offs[base + j] = run;
    cur[base + j]  = run;
    dinv[base + j] = rsqrtf((float)(c + 1));
    run += c;
  }
  if (tid == 255) offs[NNODES] = run;
}

__global__ void k_fill(const int* __restrict__ ei, int E, int* cur, int* __restrict__ csr) {
  int e = blockIdx.x * 256 + threadIdx.x;
  if (e < E) {
    int d = ei[E + e];
    int p = atomicAdd(&cur[d], 1);
    csr[p] = ei[e];
  }
}

__device__ __forceinline__ bf16x8 pack8(float4 a, float4 b) {
  union { bf16 h[8]; bf16x8 v; } u;
  u.h[0] = __float2bfloat16(a.x); u.h[1] = __float2bfloat16(a.y);
  u.h[2] = __float2bfloat16(a.z); u.h[3] = __float2bfloat16(a.w);
  u.h[4] = __float2bfloat16(b.x); u.h[5] = __float2bfloat16(b.y);
  u.h[6] = __float2bfloat16(b.z); u.h[7] = __float2bfloat16(b.w);
  return u.v;
}

// C = [x | hidden] @ [W1 | W2top] : M=8192, N=192, K=8256
// grid (64, ksplit), 256 threads = 4 waves; wave owns 32 rows x 192 cols.
// NO LDS, NO barriers: A streams HBM->reg (1-deep prefetch), B fragments read
// straight from L2-resident wct (3.1 MB). Canonical frag k-map: k = g*8+j both sides.
__global__ __launch_bounds__(256, 2) void k_gemm(const float* __restrict__ x,
                                                 const float* __restrict__ hid,
                                                 const bf16* __restrict__ wct,
                                                 float* __restrict__ yp,
                                                 bf16* __restrict__ h1d,
                                                 float* __restrict__ hx2d,
                                                 int tpc) {
  const int tid = threadIdx.x;
  const int lane = tid & 63, w = tid >> 6;
  const int rl = lane & 15, g = lane >> 4;
  const int m0 = blockIdx.x * BMB + w * 32;
  const int r0 = m0 + rl, r1 = m0 + rl + 16;
  const int chunk = blockIdx.y;
  const int t_lo = chunk * tpc;
  const int t_hi = (t_lo + tpc > KT32) ? KT32 : (t_lo + tpc);

  const float* a0x = x + (size_t)r0 * 8192 + g * 8;
  const float* a1x = x + (size_t)r1 * 8192 + g * 8;
  const float* a0h = hid + (size_t)r0 * 64 + g * 8;
  const float* a1h = hid + (size_t)r1 * 64 + g * 8;
  const bf16*  bp  = wct + (size_t)rl * FIN + g * 8;

  f32x4 acc0[12] = {};
  f32x4 acc1[12] = {};

  float4 avc[4], avn[4];
  {
    const int k0 = t_lo * 32;
    const float* p0 = (k0 < 8192) ? (a0x + k0) : (a0h + (k0 - 8192));
    const float* p1 = (k0 < 8192) ? (a1x + k0) : (a1h + (k0 - 8192));
    avc[0] = ((const float4*)p0)[0]; avc[1] = ((const float4*)p0)[1];
    avc[2] = ((const float4*)p1)[0]; avc[3] = ((const float4*)p1)[1];
  }

  for (int t = t_lo; t < t_hi; ++t) {
    const bool hn = (t + 1 < t_hi);
    if (hn) {   // prefetch next A (HBM) first — longest latency
      const int k1 = (t + 1) * 32;
      const float* p0 = (k1 < 8192) ? (a0x + k1) : (a0h + (k1 - 8192));
      const float* p1 = (k1 < 8192) ? (a1x + k1) : (a1h + (k1 - 8192));
      avn[0] = ((const float4*)p0)[0]; avn[1] = ((const float4*)p0)[1];
      avn[2] = ((const float4*)p1)[0]; avn[3] = ((const float4*)p1)[1];
    }
    // B fragments for this tile (L2)
    const bf16* bk = bp + t * 32;
    uint4 bv[12];
#pragma unroll
    for (int nf = 0; nf < 12; ++nf)
      bv[nf] = *(const uint4*)(bk + (size_t)nf * 16 * FIN);

    bf16x8 af0 = pack8(avc[0], avc[1]);
    bf16x8 af1 = pack8(avc[2], avc[3]);
#pragma unroll
    for (int nf = 0; nf < 12; ++nf) {
      bf16x8 bfr = *(const bf16x8*)&bv[nf];
      acc0[nf] = __builtin_amdgcn_mfma_f32_16x16x32_bf16(af0, bfr, acc0[nf], 0, 0, 0);
      acc1[nf] = __builtin_amdgcn_mfma_f32_16x16x32_bf16(af1, bfr, acc1[nf], 0, 0, 0);
    }
    if (hn) {
#pragma unroll
      for (int q = 0; q < 4; ++q) avc[q] = avn[q];
    }
  }

  // C/D layout (HW-verified): col = lane&15, row = (lane>>4)*4 + reg
  if (h1d) {  // direct mode (ksplit==1)
#pragma unroll
    for (int nf = 0; nf < 12; ++nf) {
      int col = nf * 16 + rl;
#pragma unroll
      for (int tt = 0; tt < 4; ++tt) {
        int ra = m0 + g * 4 + tt;
        int rb = ra + 16;
        if (col < 128) {
          h1d[(size_t)ra * 128 + col] = __float2bfloat16(acc0[nf][tt]);
          h1d[(size_t)rb * 128 + col] = __float2bfloat16(acc1[nf][tt]);
        } else {
          hx2d[(size_t)ra * 64 + (col - 128)] = acc0[nf][tt];
          hx2d[(size_t)rb * 64 + (col - 128)] = acc1[nf][tt];
        }
      }
    }
  } else {
    float* ypc = yp + (size_t)chunk * ((size_t)NNODES * NCOL);
#pragma unroll
    for (int nf = 0; nf < 12; ++nf) {
      int col = nf * 16 + rl;
#pragma unroll
      for (int tt = 0; tt < 4; ++tt) {
        int ra = m0 + g * 4 + tt;
        ypc[(size_t)ra * NCOL + col] = acc0[nf][tt];
        ypc[(size_t)(ra + 16) * NCOL + col] = acc1[nf][tt];
      }
    }
  }
}

// sum K-split partials; h1 -> bf16, hx2 -> fp32
__global__ void k_reduce(const float* __restrict__ yp, bf16* __restrict__ h1,
                         float* __restrict__ hx2, int nch) {
  int idx = blockIdx.x * 256 + threadIdx.x;  // < 8192*192
  float s = 0.f;
  for (int c = 0; c < nch; c++) s += yp[(size_t)c * ((size_t)NNODES * NCOL) + idx];
  int i = idx / NCOL, c = idx - i * NCOL;
  if (c < 128) h1[(size_t)i * 128 + c] = __float2bfloat16(s);
  else         hx2[(size_t)i * 64 + (c - 128)] = s;
}

__device__ __forceinline__ float bflo(unsigned v) { return __uint_as_float(v << 16); }
__device__ __forceinline__ float bfhi(unsigned v) { return __uint_as_float(v & 0xffff0000u); }

// one wave per node: ru = sigmoid(selfloop + sum_edges h1[src]*dinv[src]*dinv[dst] + b1)
__global__ void k_scat1(const bf16* __restrict__ h1b, const int* __restrict__ offs,
                        const int* __restrict__ csr, const float* __restrict__ dinv,
                        const float* __restrict__ b1, float* __restrict__ ru) {
  int node = blockIdx.x * 4 + (threadIdx.x >> 6);
  int lane = threadIdx.x & 63;
  const unsigned* h1u = (const unsigned*)h1b;   // 64 uints per row
  float dd = dinv[node];
  unsigned vv = h1u[(size_t)node * 64 + lane];
  float ax = bflo(vv) * dd * dd, ay = bfhi(vv) * dd * dd;
  int e0 = offs[node], e1 = offs[node + 1];
  for (int e = e0; e < e1; ++e) {
    int s = csr[e];
    float nrm = dinv[s] * dd;
    unsigned wv = h1u[(size_t)s * 64 + lane];
    ax += bflo(wv) * nrm;
    ay += bfhi(wv) * nrm;
  }
  ax += b1[lane * 2];
  ay += b1[lane * 2 + 1];
  ax = 1.f / (1.f + expf(-ax));
  ay = 1.f / (1.f + expf(-ay));
  ru[(size_t)node * 128 + lane * 2]     = ax;
  ru[(size_t)node * 128 + lane * 2 + 1] = ay;
}

// h2[i] = hx2[i] + (r[i] .* hidden[i]) @ W2_bottom  (r via the flat-reshape quirk)
__global__ void k_rh(const float* __restrict__ ru, const float* __restrict__ hidden,
                     const float* __restrict__ hx2, const float* __restrict__ W2,
                     bf16* __restrict__ h2) {
  __shared__ float W2s[64][64];
  __shared__ float rhs[4][64];
  int tid = threadIdx.x;
#pragma unroll
  for (int t = 0; t < 16; ++t) {
    int idx = tid + 256 * t;  // 4096
    int j = idx >> 6, c = idx & 63;
    W2s[j][c] = W2[(size_t)(8192 + j) * 64 + c];
  }
  int w = tid >> 6, lane = tid & 63;
  int i = blockIdx.x * 4 + w;
  float rv = ru[(size_t)(i >> 1) * 128 + ((i & 1) << 6) + lane];
  float hv = hidden[(size_t)i * 64 + lane];
  rhs[w][lane] = rv * hv;
  __syncthreads();
  float acc = hx2[(size_t)i * 64 + lane];
#pragma unroll 8
  for (int j = 0; j < 64; ++j) acc += rhs[w][j] * W2s[j][lane];
  h2[(size_t)i * 64 + lane] = __float2bfloat16(acc);
}

// one wave per node: c = tanh(gather(h2)+b2); out = u*h + (1-u)*c  (u via reshape quirk)
__global__ void k_scat2(const bf16* __restrict__ h2b, const int* __restrict__ offs,
                        const int* __restrict__ csr, const float* __restrict__ dinv,
                        const float* __restrict__ b2, const float* __restrict__ ru,
                        const float* __restrict__ hidden, float* __restrict__ out) {
  int node = blockIdx.x * 4 + (threadIdx.x >> 6);
  int lane = threadIdx.x & 63;
  const unsigned short* h2u = (const unsigned short*)h2b;
  float dd = dinv[node];
  float acc = bflo((unsigned)h2u[(size_t)node * 64 + lane]) * dd * dd;
  int e0 = offs[node], e1 = offs[node + 1];
  for (int e = e0; e < e1; ++e) {
    int s = csr[e];
    acc += bflo((unsigned)h2u[(size_t)s * 64 + lane]) * dinv[s] * dd;
  }
  acc += b2[lane];
  float cv = tanhf(acc);
  float u = ru[(size_t)(4096 + (node >> 1)) * 128 + ((node & 1) << 6) + lane];
  float hv = hidden[(size_t)node * 64 + lane];
  out[(size_t)node * 64 + lane] = u * hv + (1.f - u) * cv;
}

extern "C" void kernel_launch(void* const* d_in, const int* in_sizes, int n_in,
                              void* d_out, int out_size, void* d_ws, size_t ws_size,
                              hipStream_t stream) {
  (void)n_in; (void)out_size;
  const float* x   = (const float*)d_in[0];
  const float* hid = (const float*)d_in[1];
  const float* W1  = (const float*)d_in[2];
  const float* b1  = (const float*)d_in[3];
  const float* W2  = (const float*)d_in[4];
  const float* b2  = (const float*)d_in[5];
  const int*   ei  = (const int*)d_in[6];
  const int E = in_sizes[6] / 2;
  float* out = (float*)d_out;

  int ksplit;
  if      (ws_size >= YP_OFF + 8ull * YP_SLICE) ksplit = 8;
  else if (ws_size >= YP_OFF + 4ull * YP_SLICE) ksplit = 4;
  else if (ws_size >= YP_OFF + 2ull * YP_SLICE) ksplit = 2;
  else if (ws_size >= YP_OFF)                   ksplit = 1;   // direct mode
  else {
    k_out_zero<<<dim3(NNODES * 64 / 256), dim3(256), 0, stream>>>(out);
    return;
  }
  const int tpc = (KT32 + ksplit - 1) / ksplit;

  char* ws = (char*)d_ws;
  bf16*  wct  = (bf16*)(ws + WCT_OFF);
  int*   cnt  = (int*)(ws + CNT_OFF);
  int*   offs = (int*)(ws + OFF_OFF);
  int*   cur  = (int*)(ws + CUR_OFF);
  float* dinv = (float*)(ws + DNV_OFF);
  int*   csr  = (int*)(ws + CSR_OFF);
  bf16*  h1   = (bf16*)(ws + H1_OFF);
  float* hx2  = (float*)(ws + HX2_OFF);
  float* ru   = (float*)(ws + RU_OFF);
  bf16*  h2   = (bf16*)(ws + H2_OFF);
  float* yp   = (float*)(ws + YP_OFF);

  k_zero_i<<<dim3(32), dim3(256), 0, stream>>>(cnt, NNODES);
  k_prep_wct<<<dim3(FIN / 32, NCOL / 32), dim3(256), 0, stream>>>(W1, W2, wct);
  k_hist<<<dim3((E + 255) / 256), dim3(256), 0, stream>>>(ei, E, cnt);
  k_scan<<<dim3(1), dim3(256), 0, stream>>>(cnt, offs, cur, dinv);
  k_fill<<<dim3((E + 255) / 256), dim3(256), 0, stream>>>(ei, E, cur, csr);
  if (ksplit == 1) {
    k_gemm<<<dim3(NNODES / BMB, 1), dim3(256), 0, stream>>>(x, hid, wct, nullptr, h1, hx2, tpc);
  } else {
    k_gemm<<<dim3(NNODES / BMB, ksplit), dim3(256), 0, stream>>>(x, hid, wct, yp, nullptr, nullptr, tpc);
    k_reduce<<<dim3(NNODES * NCOL / 256), dim3(256), 0, stream>>>(yp, h1, hx2, ksplit);
  }
  k_scat1<<<dim3(NNODES / 4), dim3(256), 0, stream>>>(h1, offs, csr, dinv, b1, ru);
  k_rh<<<dim3(NNODES / 4), dim3(256), 0, stream>>>(ru, hid, hx2, W2, h2);
  k_scat2<<<dim3(NNODES / 4), dim3(256), 0, stream>>>(h2, offs, csr, dinv, b2, ru, hid, out);
}

// Round 6
// 247.313 us; speedup vs baseline: 1.2059x; 1.0669x over previous
//
#include <hip/hip_runtime.h>
#include <hip/hip_bf16.h>
#include <stdint.h>

typedef __bf16 bf16x8 __attribute__((ext_vector_type(8)));
typedef float  f32x4  __attribute__((ext_vector_type(4)));
using bf16 = __hip_bfloat16;

#define NNODES 8192
#define FIN    8256      // 8192 + 64
#define NCOL   192       // 128 (W1) + 64 (W2 top)
#define KT32   258       // 8256 / 32
#define BMB    128       // rows per block (4 waves x 32 rows)

// ---- workspace layout (bytes) ----
enum : size_t {
  WCT_OFF  = 0,            // bf16 wctf [258][12][64][8]  3,170,304
  CNT_OFF  = 3170304,      // int  [8192]
  OFF_OFF  = 3203072,      // int  [8193]
  CUR_OFF  = 3236096,      // int  [8192]
  DNV_OFF  = 3268864,      // f32  [8192]
  CSR_OFF  = 3301632,      // int  [262144]
  H1_OFF   = 4350208,      // bf16 [8192][128]
  HX2_OFF  = 8544512,      // f32  [8192][64]
  RU_OFF   = 10641664,     // f32  [8192][128]
  H2_OFF   = 14835968,     // bf16 [8192][64]
  YP_OFF   = 16933120,     // f32  [ksplit][8192][192]
  YP_SLICE = 6291456
};

__global__ void k_zero_i(int* p, int n) {
  int i = blockIdx.x * 256 + threadIdx.x;
  if (i < n) p[i] = 0;
}

__global__ void k_out_zero(float* out) {
  int i = blockIdx.x * 256 + threadIdx.x;
  if (i < NNODES * 64) out[i] = 0.f;   // diagnostic signature if ws too small
}

// Build B in MFMA-fragment order: wctf[((t*12+nf)*64+lane)*8+j] =
//   Wc[k = t*32 + (lane>>4)*8 + j][col = nf*16 + (lane&15)]
// where Wc[k][c] = c<128 ? W1[k][c] : (k<8192 ? W2[k][c-128] : 0)
__global__ void k_prep_wctf(const float* __restrict__ W1, const float* __restrict__ W2,
                            bf16* __restrict__ wctf) {
  int gid = blockIdx.x * 256 + threadIdx.x;
  if (gid >= KT32 * 12 * 64) return;
  int t = gid / 768;
  int rem = gid - t * 768;
  int nf = rem >> 6, lane = rem & 63;
  int col = nf * 16 + (lane & 15);
  int k0 = t * 32 + (lane >> 4) * 8;
  union { bf16 h[8]; uint4 v; } u;
#pragma unroll
  for (int j = 0; j < 8; ++j) {
    int k = k0 + j;
    float v;
    if (col < 128)      v = W1[(size_t)k * 128 + col];
    else if (k < 8192)  v = W2[(size_t)k * 64 + (col - 128)];
    else                v = 0.f;
    u.h[j] = __float2bfloat16(v);
  }
  *(uint4*)(wctf + (size_t)gid * 8) = u.v;
}

__global__ void k_hist(const int* __restrict__ ei, int E, int* cnt) {
  int e = blockIdx.x * 256 + threadIdx.x;
  if (e < E) atomicAdd(&cnt[ei[E + e]], 1);
}

__global__ void k_scan(const int* __restrict__ cnt, int* __restrict__ offs,
                       int* __restrict__ cur, float* __restrict__ dinv) {
  __shared__ int part[256];
  int tid = threadIdx.x;
  int base = tid * 32;
  int s = 0;
#pragma unroll
  for (int j = 0; j < 32; j++) s += cnt[base + j];
  part[tid] = s;
  __syncthreads();
  for (int off = 1; off < 256; off <<= 1) {
    int a = (tid >= off) ? part[tid - off] : 0;
    __syncthreads();
    part[tid] += a;
    __syncthreads();
  }
  int run = (tid == 0) ? 0 : part[tid - 1];
  for (int j = 0; j < 32; j++) {
    int c = cnt[base + j];
    offs[base + j] = run;
    cur[base + j]  = run;
    dinv[base + j] = rsqrtf((float)(c + 1));
    run += c;
  }
  if (tid == 255) offs[NNODES] = run;
}

__global__ void k_fill(const int* __restrict__ ei, int E, int* cur, int* __restrict__ csr) {
  int e = blockIdx.x * 256 + threadIdx.x;
  if (e < E) {
    int d = ei[E + e];
    int p = atomicAdd(&cur[d], 1);
    csr[p] = ei[e];
  }
}

__device__ __forceinline__ bf16x8 pack8(float4 a, float4 b) {
  union { bf16 h[8]; bf16x8 v; } u;
  u.h[0] = __float2bfloat16(a.x); u.h[1] = __float2bfloat16(a.y);
  u.h[2] = __float2bfloat16(a.z); u.h[3] = __float2bfloat16(a.w);
  u.h[4] = __float2bfloat16(b.x); u.h[5] = __float2bfloat16(b.y);
  u.h[6] = __float2bfloat16(b.z); u.h[7] = __float2bfloat16(b.w);
  return u.v;
}

// C = [x | hidden] @ Wc : M=8192, N=192, K=8256
// grid (64, ksplit), 256 threads = 4 waves; wave owns 32 rows x 192 cols.
// No LDS, no barriers. Per iter: 12 CONTIGUOUS 1KB B loads (fragment-packed wctf,
// L2-resident) issued FIRST, then 4 A loads for t+1 (HBM) -- so consuming B waits
// only vmcnt(4) and A stays in flight across the iteration boundary.
__global__ __launch_bounds__(256, 2) void k_gemm(const float* __restrict__ x,
                                                 const float* __restrict__ hid,
                                                 const bf16* __restrict__ wctf,
                                                 float* __restrict__ yp,
                                                 bf16* __restrict__ h1d,
                                                 float* __restrict__ hx2d,
                                                 int tpc) {
  const int tid = threadIdx.x;
  const int lane = tid & 63, w = tid >> 6;
  const int rl = lane & 15, g = lane >> 4;
  const int m0 = blockIdx.x * BMB + w * 32;
  const int r0 = m0 + rl, r1 = m0 + rl + 16;
  const int chunk = blockIdx.y;
  const int t_lo = chunk * tpc;
  const int t_hi = (t_lo + tpc > KT32) ? KT32 : (t_lo + tpc);

  const float* a0x = x + (size_t)r0 * 8192 + g * 8;
  const float* a1x = x + (size_t)r1 * 8192 + g * 8;
  const float* a0h = hid + (size_t)r0 * 64 + g * 8;
  const float* a1h = hid + (size_t)r1 * 64 + g * 8;
  const bf16*  bl  = wctf + (size_t)lane * 8;   // + t*6144 + nf*512

  f32x4 acc0[12] = {};
  f32x4 acc1[12] = {};

  float4 avc[4], avn[4];
  {
    const int k0 = t_lo * 32;
    const float* p0 = (k0 < 8192) ? (a0x + k0) : (a0h + (k0 - 8192));
    const float* p1 = (k0 < 8192) ? (a1x + k0) : (a1h + (k0 - 8192));
    avc[0] = ((const float4*)p0)[0]; avc[1] = ((const float4*)p0)[1];
    avc[2] = ((const float4*)p1)[0]; avc[3] = ((const float4*)p1)[1];
  }

#pragma unroll 2
  for (int t = t_lo; t < t_hi; ++t) {
    // ---- B(t): 12 contiguous 1KB loads, issued first ----
    const bf16* bt = bl + (size_t)t * 6144;
    uint4 bv[12];
#pragma unroll
    for (int nf = 0; nf < 12; ++nf)
      bv[nf] = *(const uint4*)(bt + (size_t)nf * 512);

    // ---- A(t+1) prefetch: issued AFTER B so B-waits don't drain it ----
    const bool hn = (t + 1 < t_hi);
    if (hn) {
      const int k1 = (t + 1) * 32;
      const float* p0 = (k1 < 8192) ? (a0x + k1) : (a0h + (k1 - 8192));
      const float* p1 = (k1 < 8192) ? (a1x + k1) : (a1h + (k1 - 8192));
      avn[0] = ((const float4*)p0)[0]; avn[1] = ((const float4*)p0)[1];
      avn[2] = ((const float4*)p1)[0]; avn[3] = ((const float4*)p1)[1];
    }
    asm volatile("" ::: "memory");   // pin batch issue: loads can't sink below

    bf16x8 af0 = pack8(avc[0], avc[1]);
    bf16x8 af1 = pack8(avc[2], avc[3]);
#pragma unroll
    for (int nf = 0; nf < 12; ++nf) {
      bf16x8 bfr = *(const bf16x8*)&bv[nf];
      acc0[nf] = __builtin_amdgcn_mfma_f32_16x16x32_bf16(af0, bfr, acc0[nf], 0, 0, 0);
      acc1[nf] = __builtin_amdgcn_mfma_f32_16x16x32_bf16(af1, bfr, acc1[nf], 0, 0, 0);
    }
    if (hn) {
#pragma unroll
      for (int q = 0; q < 4; ++q) avc[q] = avn[q];
    }
  }

  // C/D layout (HW-verified): col = lane&15, row = (lane>>4)*4 + reg
  if (h1d) {  // direct mode (ksplit==1)
#pragma unroll
    for (int nf = 0; nf < 12; ++nf) {
      int col = nf * 16 + rl;
#pragma unroll
      for (int tt = 0; tt < 4; ++tt) {
        int ra = m0 + g * 4 + tt;
        int rb = ra + 16;
        if (col < 128) {
          h1d[(size_t)ra * 128 + col] = __float2bfloat16(acc0[nf][tt]);
          h1d[(size_t)rb * 128 + col] = __float2bfloat16(acc1[nf][tt]);
        } else {
          hx2d[(size_t)ra * 64 + (col - 128)] = acc0[nf][tt];
          hx2d[(size_t)rb * 64 + (col - 128)] = acc1[nf][tt];
        }
      }
    }
  } else {
    float* ypc = yp + (size_t)chunk * ((size_t)NNODES * NCOL);
#pragma unroll
    for (int nf = 0; nf < 12; ++nf) {
      int col = nf * 16 + rl;
#pragma unroll
      for (int tt = 0; tt < 4; ++tt) {
        int ra = m0 + g * 4 + tt;
        ypc[(size_t)ra * NCOL + col] = acc0[nf][tt];
        ypc[(size_t)(ra + 16) * NCOL + col] = acc1[nf][tt];
      }
    }
  }
}

// sum K-split partials; h1 -> bf16, hx2 -> fp32
__global__ void k_reduce(const float* __restrict__ yp, bf16* __restrict__ h1,
                         float* __restrict__ hx2, int nch) {
  int idx = blockIdx.x * 256 + threadIdx.x;  // < 8192*192
  float s = 0.f;
  for (int c = 0; c < nch; c++) s += yp[(size_t)c * ((size_t)NNODES * NCOL) + idx];
  int i = idx / NCOL, c = idx - i * NCOL;
  if (c < 128) h1[(size_t)i * 128 + c] = __float2bfloat16(s);
  else         hx2[(size_t)i * 64 + (c - 128)] = s;
}

__device__ __forceinline__ float bflo(unsigned v) { return __uint_as_float(v << 16); }
__device__ __forceinline__ float bfhi(unsigned v) { return __uint_as_float(v & 0xffff0000u); }

// one wave per node: ru = sigmoid(selfloop + sum_edges h1[src]*dinv[src]*dinv[dst] + b1)
__global__ void k_scat1(const bf16* __restrict__ h1b, const int* __restrict__ offs,
                        const int* __restrict__ csr, const float* __restrict__ dinv,
                        const float* __restrict__ b1, float* __restrict__ ru) {
  int node = blockIdx.x * 4 + (threadIdx.x >> 6);
  int lane = threadIdx.x & 63;
  const unsigned* h1u = (const unsigned*)h1b;   // 64 uints per row
  float dd = dinv[node];
  unsigned vv = h1u[(size_t)node * 64 + lane];
  float ax = bflo(vv) * dd * dd, ay = bfhi(vv) * dd * dd;
  int e0 = offs[node], e1 = offs[node + 1];
  for (int e = e0; e < e1; ++e) {
    int s = csr[e];
    float nrm = dinv[s] * dd;
    unsigned wv = h1u[(size_t)s * 64 + lane];
    ax += bflo(wv) * nrm;
    ay += bfhi(wv) * nrm;
  }
  ax += b1[lane * 2];
  ay += b1[lane * 2 + 1];
  ax = 1.f / (1.f + expf(-ax));
  ay = 1.f / (1.f + expf(-ay));
  ru[(size_t)node * 128 + lane * 2]     = ax;
  ru[(size_t)node * 128 + lane * 2 + 1] = ay;
}

// h2[i] = hx2[i] + (r[i] .* hidden[i]) @ W2_bottom  (r via the flat-reshape quirk)
__global__ void k_rh(const float* __restrict__ ru, const float* __restrict__ hidden,
                     const float* __restrict__ hx2, const float* __restrict__ W2,
                     bf16* __restrict__ h2) {
  __shared__ float W2s[64][64];
  __shared__ float rhs[4][64];
  int tid = threadIdx.x;
#pragma unroll
  for (int t = 0; t < 16; ++t) {
    int idx = tid + 256 * t;  // 4096
    int j = idx >> 6, c = idx & 63;
    W2s[j][c] = W2[(size_t)(8192 + j) * 64 + c];
  }
  int w = tid >> 6, lane = tid & 63;
  int i = blockIdx.x * 4 + w;
  float rv = ru[(size_t)(i >> 1) * 128 + ((i & 1) << 6) + lane];
  float hv = hidden[(size_t)i * 64 + lane];
  rhs[w][lane] = rv * hv;
  __syncthreads();
  float acc = hx2[(size_t)i * 64 + lane];
#pragma unroll 8
  for (int j = 0; j < 64; ++j) acc += rhs[w][j] * W2s[j][lane];
  h2[(size_t)i * 64 + lane] = __float2bfloat16(acc);
}

// one wave per node: c = tanh(gather(h2)+b2); out = u*h + (1-u)*c  (u via reshape quirk)
__global__ void k_scat2(const bf16* __restrict__ h2b, const int* __restrict__ offs,
                        const int* __restrict__ csr, const float* __restrict__ dinv,
                        const float* __restrict__ b2, const float* __restrict__ ru,
                        const float* __restrict__ hidden, float* __restrict__ out) {
  int node = blockIdx.x * 4 + (threadIdx.x >> 6);
  int lane = threadIdx.x & 63;
  const unsigned short* h2u = (const unsigned short*)h2b;
  float dd = dinv[node];
  float acc = bflo((unsigned)h2u[(size_t)node * 64 + lane]) * dd * dd;
  int e0 = offs[node], e1 = offs[node + 1];
  for (int e = e0; e < e1; ++e) {
    int s = csr[e];
    acc += bflo((unsigned)h2u[(size_t)s * 64 + lane]) * dinv[s] * dd;
  }
  acc += b2[lane];
  float cv = tanhf(acc);
  float u = ru[(size_t)(4096 + (node >> 1)) * 128 + ((node & 1) << 6) + lane];
  float hv = hidden[(size_t)node * 64 + lane];
  out[(size_t)node * 64 + lane] = u * hv + (1.f - u) * cv;
}

extern "C" void kernel_launch(void* const* d_in, const int* in_sizes, int n_in,
                              void* d_out, int out_size, void* d_ws, size_t ws_size,
                              hipStream_t stream) {
  (void)n_in; (void)out_size;
  const float* x   = (const float*)d_in[0];
  const float* hid = (const float*)d_in[1];
  const float* W1  = (const float*)d_in[2];
  const float* b1  = (const float*)d_in[3];
  const float* W2  = (const float*)d_in[4];
  const float* b2  = (const float*)d_in[5];
  const int*   ei  = (const int*)d_in[6];
  const int E = in_sizes[6] / 2;
  float* out = (float*)d_out;

  int ksplit;
  if      (ws_size >= YP_OFF + 8ull * YP_SLICE) ksplit = 8;
  else if (ws_size >= YP_OFF + 4ull * YP_SLICE) ksplit = 4;
  else if (ws_size >= YP_OFF + 2ull * YP_SLICE) ksplit = 2;
  else if (ws_size >= YP_OFF)                   ksplit = 1;   // direct mode
  else {
    k_out_zero<<<dim3(NNODES * 64 / 256), dim3(256), 0, stream>>>(out);
    return;
  }
  const int tpc = (KT32 + ksplit - 1) / ksplit;

  char* ws = (char*)d_ws;
  bf16*  wctf = (bf16*)(ws + WCT_OFF);
  int*   cnt  = (int*)(ws + CNT_OFF);
  int*   offs = (int*)(ws + OFF_OFF);
  int*   cur  = (int*)(ws + CUR_OFF);
  float* dinv = (float*)(ws + DNV_OFF);
  int*   csr  = (int*)(ws + CSR_OFF);
  bf16*  h1   = (bf16*)(ws + H1_OFF);
  float* hx2  = (float*)(ws + HX2_OFF);
  float* ru   = (float*)(ws + RU_OFF);
  bf16*  h2   = (bf16*)(ws + H2_OFF);
  float* yp   = (float*)(ws + YP_OFF);

  k_zero_i<<<dim3(32), dim3(256), 0, stream>>>(cnt, NNODES);
  k_prep_wctf<<<dim3((KT32 * 12 * 64 + 255) / 256), dim3(256), 0, stream>>>(W1, W2, wctf);
  k_hist<<<dim3((E + 255) / 256), dim3(256), 0, stream>>>(ei, E, cnt);
  k_scan<<<dim3(1), dim3(256), 0, stream>>>(cnt, offs, cur, dinv);
  k_fill<<<dim3((E + 255) / 256), dim3(256), 0, stream>>>(ei, E, cur, csr);
  if (ksplit == 1) {
    k_gemm<<<dim3(NNODES / BMB, 1), dim3(256), 0, stream>>>(x, hid, wctf, nullptr, h1, hx2, tpc);
  } else {
    k_gemm<<<dim3(NNODES / BMB, ksplit), dim3(256), 0, stream>>>(x, hid, wctf, yp, nullptr, nullptr, tpc);
    k_reduce<<<dim3(NNODES * NCOL / 256), dim3(256), 0, stream>>>(yp, h1, hx2, ksplit);
  }
  k_scat1<<<dim3(NNODES / 4), dim3(256), 0, stream>>>(h1, offs, csr, dinv, b1, ru);
  k_rh<<<dim3(NNODES / 4), dim3(256), 0, stream>>>(ru, hid, hx2, W2, h2);
  k_scat2<<<dim3(NNODES / 4), dim3(256), 0, stream>>>(h2, offs, csr, dinv, b2, ru, hid, out);
}

// Round 7
// 212.234 us; speedup vs baseline: 1.4053x; 1.1653x over previous
//
#include <hip/hip_runtime.h>
#include <hip/hip_bf16.h>
#include <stdint.h>

typedef __bf16 bf16x8 __attribute__((ext_vector_type(8)));
typedef float  f32x4  __attribute__((ext_vector_type(4)));
using bf16 = __hip_bfloat16;

#define NNODES 8192
#define FIN    8256      // 8192 + 64
#define NCOL   192       // 128 (W1) + 64 (W2 top)
#define KT32   258       // 8256 / 32
#define BMB    128       // rows per block (4 waves x 32 rows)

// ---- workspace layout (bytes) ----
enum : size_t {
  WCT_OFF  = 0,            // bf16 wctf [258][12][64][8]  3,170,304
  CNT_OFF  = 3170304,      // int  [8192]
  OFF_OFF  = 3203072,      // int  [8193]
  CUR_OFF  = 3236096,      // int  [8192]
  DNV_OFF  = 3268864,      // f32  [8192]
  CSR_OFF  = 3301632,      // int  [262144]
  H1_OFF   = 4350208,      // bf16 [8192][128]
  HX2_OFF  = 8544512,      // f32  [8192][64]
  RU_OFF   = 10641664,     // f32  [8192][128]
  H2_OFF   = 14835968,     // bf16 [8192][64]
  YP_OFF   = 16933120,     // f32  [ksplit][8192][192]
  YP_SLICE = 6291456
};

__global__ void k_zero_i(int* p, int n) {
  int i = blockIdx.x * 256 + threadIdx.x;
  if (i < n) p[i] = 0;
}

__global__ void k_out_zero(float* out) {
  int i = blockIdx.x * 256 + threadIdx.x;
  if (i < NNODES * 64) out[i] = 0.f;   // diagnostic signature if ws too small
}

// Build B in MFMA-fragment order: wctf[((t*12+nf)*64+lane)*8+j] =
//   Wc[k = t*32 + (lane>>4)*8 + j][col = nf*16 + (lane&15)]
// where Wc[k][c] = c<128 ? W1[k][c] : (k<8192 ? W2[k][c-128] : 0)
__global__ void k_prep_wctf(const float* __restrict__ W1, const float* __restrict__ W2,
                            bf16* __restrict__ wctf) {
  int gid = blockIdx.x * 256 + threadIdx.x;
  if (gid >= KT32 * 12 * 64) return;
  int t = gid / 768;
  int rem = gid - t * 768;
  int nf = rem >> 6, lane = rem & 63;
  int col = nf * 16 + (lane & 15);
  int k0 = t * 32 + (lane >> 4) * 8;
  union { bf16 h[8]; uint4 v; } u;
#pragma unroll
  for (int j = 0; j < 8; ++j) {
    int k = k0 + j;
    float v;
    if (col < 128)      v = W1[(size_t)k * 128 + col];
    else if (k < 8192)  v = W2[(size_t)k * 64 + (col - 128)];
    else                v = 0.f;
    u.h[j] = __float2bfloat16(v);
  }
  *(uint4*)(wctf + (size_t)gid * 8) = u.v;
}

__global__ void k_hist(const int* __restrict__ ei, int E, int* cnt) {
  int e = blockIdx.x * 256 + threadIdx.x;
  if (e < E) atomicAdd(&cnt[ei[E + e]], 1);
}

__global__ void k_scan(const int* __restrict__ cnt, int* __restrict__ offs,
                       int* __restrict__ cur, float* __restrict__ dinv) {
  __shared__ int part[256];
  int tid = threadIdx.x;
  int base = tid * 32;
  int s = 0;
#pragma unroll
  for (int j = 0; j < 32; j++) s += cnt[base + j];
  part[tid] = s;
  __syncthreads();
  for (int off = 1; off < 256; off <<= 1) {
    int a = (tid >= off) ? part[tid - off] : 0;
    __syncthreads();
    part[tid] += a;
    __syncthreads();
  }
  int run = (tid == 0) ? 0 : part[tid - 1];
  for (int j = 0; j < 32; j++) {
    int c = cnt[base + j];
    offs[base + j] = run;
    cur[base + j]  = run;
    dinv[base + j] = rsqrtf((float)(c + 1));
    run += c;
  }
  if (tid == 255) offs[NNODES] = run;
}

__global__ void k_fill(const int* __restrict__ ei, int E, int* cur, int* __restrict__ csr) {
  int e = blockIdx.x * 256 + threadIdx.x;
  if (e < E) {
    int d = ei[E + e];
    int p = atomicAdd(&cur[d], 1);
    csr[p] = ei[e];
  }
}

__device__ __forceinline__ bf16x8 pack8(float4 a, float4 b) {
  union { bf16 h[8]; bf16x8 v; } u;
  u.h[0] = __float2bfloat16(a.x); u.h[1] = __float2bfloat16(a.y);
  u.h[2] = __float2bfloat16(a.z); u.h[3] = __float2bfloat16(a.w);
  u.h[4] = __float2bfloat16(b.x); u.h[5] = __float2bfloat16(b.y);
  u.h[6] = __float2bfloat16(b.z); u.h[7] = __float2bfloat16(b.w);
  return u.v;
}

__device__ __forceinline__ void gld16(void* ldsdst, const void* gsrc) {
  __builtin_amdgcn_global_load_lds(
      (__attribute__((address_space(1))) void*)gsrc,
      (__attribute__((address_space(3))) void*)ldsdst, 16, 0, 0);
}

// C = [x | hidden] @ Wc : M=8192, N=192, K=8256
// m97-style: A (fp32, HBM) -> LDS via global_load_lds w16, double-buffered,
// pre-swizzled source (slot s of row holds elems (s^(row&7))*4) so swizzled
// ds_read is conflict-free(2-way). B from fragment-packed wctf (L2) via DMA too.
// 256 threads / 4 waves; wave w: rows w*32..w*32+31, all 192 cols. BK=32.
// One __syncthreads per K-step (vmcnt drain amortized by 2 blocks/CU).
__global__ __launch_bounds__(256, 2) void k_gemm(const float* __restrict__ x,
                                                 const float* __restrict__ hid,
                                                 const bf16* __restrict__ wctf,
                                                 float* __restrict__ yp,
                                                 bf16* __restrict__ h1d,
                                                 float* __restrict__ hx2d,
                                                 int tpc) {
  __shared__ uint4 smA[2][1024];   // 2 x 16 KB fp32 A tile [128 rows][8 slots of 16B]
  __shared__ uint4 smB[2][768];    // 2 x 12 KB bf16 B tile (fragment-packed)
  const int tid = threadIdx.x;
  const int lane = tid & 63, w = tid >> 6;
  const int rl = lane & 15, g = lane >> 4;
  const int m0 = blockIdx.x * BMB;
  const int chunk = blockIdx.y;
  const int t_lo = chunk * tpc;
  const int t_hi = (t_lo + tpc > KT32) ? KT32 : (t_lo + tpc);
  const int nt = t_hi - t_lo;

  // A staging sources (pre-swizzled): unit u = q*256+tid -> row=u>>3, slot s=u&7
  const float* asx[4]; const float* ash[4];
#pragma unroll
  for (int q = 0; q < 4; ++q) {
    int u = q * 256 + tid, row = u >> 3, s = u & 7;
    int sel = (s ^ (row & 7)) << 2;     // fp32 element offset within 32-elem tile
    asx[q] = x + (size_t)(m0 + row) * 8192 + sel;
    ash[q] = hid + (size_t)(m0 + row) * 64 + sel;
  }

  f32x4 acc0[12] = {};
  f32x4 acc1[12] = {};

  // fragment read slot indices (XOR involution matches staging pre-swizzle)
  const int sl0 = (g * 2) ^ (rl & 7);
  const int sl1 = (g * 2 + 1) ^ (rl & 7);
  const int ra0 = (w * 32 + rl) * 8;
  const int ra1 = (w * 32 + 16 + rl) * 8;

#define STAGE(b, t) do {                                                        \
    const int _t = (t);                                                         \
    if (_t < 256) {                                                             \
      const int _k = _t * 32;                                                   \
      _Pragma("unroll")                                                         \
      for (int q = 0; q < 4; ++q) gld16(&smA[b][q * 256 + tid], asx[q] + _k);   \
    } else {                                                                    \
      const int _k = (_t - 256) * 32;                                           \
      _Pragma("unroll")                                                         \
      for (int q = 0; q < 4; ++q) gld16(&smA[b][q * 256 + tid], ash[q] + _k);   \
    }                                                                           \
    const bf16* _bt = wctf + (size_t)_t * 6144;                                 \
    _Pragma("unroll")                                                           \
    for (int q = 0; q < 3; ++q)                                                 \
      gld16(&smB[b][q * 256 + tid], _bt + (size_t)(q * 256 + tid) * 8);         \
  } while (0)

  STAGE(0, t_lo);
  __syncthreads();

  for (int it = 0; it < nt; ++it) {
    const int c = it & 1;
    if (it + 1 < nt) STAGE(c ^ 1, t_lo + it + 1);

    union { uint4 u; float4 f; } a00, a01, a10, a11;
    a00.u = smA[c][ra0 + sl0]; a01.u = smA[c][ra0 + sl1];
    a10.u = smA[c][ra1 + sl0]; a11.u = smA[c][ra1 + sl1];
    bf16x8 af0 = pack8(a00.f, a01.f);
    bf16x8 af1 = pack8(a10.f, a11.f);
#pragma unroll
    for (int nf = 0; nf < 12; ++nf) {
      bf16x8 bfr = *(const bf16x8*)&smB[c][nf * 64 + lane];
      acc0[nf] = __builtin_amdgcn_mfma_f32_16x16x32_bf16(af0, bfr, acc0[nf], 0, 0, 0);
      acc1[nf] = __builtin_amdgcn_mfma_f32_16x16x32_bf16(af1, bfr, acc1[nf], 0, 0, 0);
    }
    __syncthreads();
  }
#undef STAGE

  // C/D layout (HW-verified): col = lane&15, row = (lane>>4)*4 + reg
  if (h1d) {  // direct mode (ksplit==1)
#pragma unroll
    for (int nf = 0; nf < 12; ++nf) {
      int col = nf * 16 + rl;
#pragma unroll
      for (int tt = 0; tt < 4; ++tt) {
        int ra = m0 + w * 32 + g * 4 + tt;
        int rb = ra + 16;
        if (col < 128) {
          h1d[(size_t)ra * 128 + col] = __float2bfloat16(acc0[nf][tt]);
          h1d[(size_t)rb * 128 + col] = __float2bfloat16(acc1[nf][tt]);
        } else {
          hx2d[(size_t)ra * 64 + (col - 128)] = acc0[nf][tt];
          hx2d[(size_t)rb * 64 + (col - 128)] = acc1[nf][tt];
        }
      }
    }
  } else {
    float* ypc = yp + (size_t)chunk * ((size_t)NNODES * NCOL);
#pragma unroll
    for (int nf = 0; nf < 12; ++nf) {
      int col = nf * 16 + rl;
#pragma unroll
      for (int tt = 0; tt < 4; ++tt) {
        int ra = m0 + w * 32 + g * 4 + tt;
        ypc[(size_t)ra * NCOL + col] = acc0[nf][tt];
        ypc[(size_t)(ra + 16) * NCOL + col] = acc1[nf][tt];
      }
    }
  }
}

// sum K-split partials; h1 -> bf16, hx2 -> fp32
__global__ void k_reduce(const float* __restrict__ yp, bf16* __restrict__ h1,
                         float* __restrict__ hx2, int nch) {
  int idx = blockIdx.x * 256 + threadIdx.x;  // < 8192*192
  float s = 0.f;
  for (int c = 0; c < nch; c++) s += yp[(size_t)c * ((size_t)NNODES * NCOL) + idx];
  int i = idx / NCOL, c = idx - i * NCOL;
  if (c < 128) h1[(size_t)i * 128 + c] = __float2bfloat16(s);
  else         hx2[(size_t)i * 64 + (c - 128)] = s;
}

__device__ __forceinline__ float bflo(unsigned v) { return __uint_as_float(v << 16); }
__device__ __forceinline__ float bfhi(unsigned v) { return __uint_as_float(v & 0xffff0000u); }

// one wave per node: ru = sigmoid(selfloop + sum_edges h1[src]*dinv[src]*dinv[dst] + b1)
__global__ void k_scat1(const bf16* __restrict__ h1b, const int* __restrict__ offs,
                        const int* __restrict__ csr, const float* __restrict__ dinv,
                        const float* __restrict__ b1, float* __restrict__ ru) {
  int node = blockIdx.x * 4 + (threadIdx.x >> 6);
  int lane = threadIdx.x & 63;
  const unsigned* h1u = (const unsigned*)h1b;   // 64 uints per row
  float dd = dinv[node];
  unsigned vv = h1u[(size_t)node * 64 + lane];
  float ax = bflo(vv) * dd * dd, ay = bfhi(vv) * dd * dd;
  int e0 = offs[node], e1 = offs[node + 1];
  for (int e = e0; e < e1; ++e) {
    int s = csr[e];
    float nrm = dinv[s] * dd;
    unsigned wv = h1u[(size_t)s * 64 + lane];
    ax += bflo(wv) * nrm;
    ay += bfhi(wv) * nrm;
  }
  ax += b1[lane * 2];
  ay += b1[lane * 2 + 1];
  ax = 1.f / (1.f + expf(-ax));
  ay = 1.f / (1.f + expf(-ay));
  ru[(size_t)node * 128 + lane * 2]     = ax;
  ru[(size_t)node * 128 + lane * 2 + 1] = ay;
}

// h2[i] = hx2[i] + (r[i] .* hidden[i]) @ W2_bottom  (r via the flat-reshape quirk)
__global__ void k_rh(const float* __restrict__ ru, const float* __restrict__ hidden,
                     const float* __restrict__ hx2, const float* __restrict__ W2,
                     bf16* __restrict__ h2) {
  __shared__ float W2s[64][64];
  __shared__ float rhs[4][64];
  int tid = threadIdx.x;
#pragma unroll
  for (int t = 0; t < 16; ++t) {
    int idx = tid + 256 * t;  // 4096
    int j = idx >> 6, c = idx & 63;
    W2s[j][c] = W2[(size_t)(8192 + j) * 64 + c];
  }
  int w = tid >> 6, lane = tid & 63;
  int i = blockIdx.x * 4 + w;
  float rv = ru[(size_t)(i >> 1) * 128 + ((i & 1) << 6) + lane];
  float hv = hidden[(size_t)i * 64 + lane];
  rhs[w][lane] = rv * hv;
  __syncthreads();
  float acc = hx2[(size_t)i * 64 + lane];
#pragma unroll 8
  for (int j = 0; j < 64; ++j) acc += rhs[w][j] * W2s[j][lane];
  h2[(size_t)i * 64 + lane] = __float2bfloat16(acc);
}

// one wave per node: c = tanh(gather(h2)+b2); out = u*h + (1-u)*c  (u via reshape quirk)
__global__ void k_scat2(const bf16* __restrict__ h2b, const int* __restrict__ offs,
                        const int* __restrict__ csr, const float* __restrict__ dinv,
                        const float* __restrict__ b2, const float* __restrict__ ru,
                        const float* __restrict__ hidden, float* __restrict__ out) {
  int node = blockIdx.x * 4 + (threadIdx.x >> 6);
  int lane = threadIdx.x & 63;
  const unsigned short* h2u = (const unsigned short*)h2b;
  float dd = dinv[node];
  float acc = bflo((unsigned)h2u[(size_t)node * 64 + lane]) * dd * dd;
  int e0 = offs[node], e1 = offs[node + 1];
  for (int e = e0; e < e1; ++e) {
    int s = csr[e];
    acc += bflo((unsigned)h2u[(size_t)s * 64 + lane]) * dinv[s] * dd;
  }
  acc += b2[lane];
  float cv = tanhf(acc);
  float u = ru[(size_t)(4096 + (node >> 1)) * 128 + ((node & 1) << 6) + lane];
  float hv = hidden[(size_t)node * 64 + lane];
  out[(size_t)node * 64 + lane] = u * hv + (1.f - u) * cv;
}

extern "C" void kernel_launch(void* const* d_in, const int* in_sizes, int n_in,
                              void* d_out, int out_size, void* d_ws, size_t ws_size,
                              hipStream_t stream) {
  (void)n_in; (void)out_size;
  const float* x   = (const float*)d_in[0];
  const float* hid = (const float*)d_in[1];
  const float* W1  = (const float*)d_in[2];
  const float* b1  = (const float*)d_in[3];
  const float* W2  = (const float*)d_in[4];
  const float* b2  = (const float*)d_in[5];
  const int*   ei  = (const int*)d_in[6];
  const int E = in_sizes[6] / 2;
  float* out = (float*)d_out;

  int ksplit;
  if      (ws_size >= YP_OFF + 8ull * YP_SLICE) ksplit = 8;
  else if (ws_size >= YP_OFF + 4ull * YP_SLICE) ksplit = 4;
  else if (ws_size >= YP_OFF + 2ull * YP_SLICE) ksplit = 2;
  else if (ws_size >= YP_OFF)                   ksplit = 1;   // direct mode
  else {
    k_out_zero<<<dim3(NNODES * 64 / 256), dim3(256), 0, stream>>>(out);
    return;
  }
  const int tpc = (KT32 + ksplit - 1) / ksplit;

  char* ws = (char*)d_ws;
  bf16*  wctf = (bf16*)(ws + WCT_OFF);
  int*   cnt  = (int*)(ws + CNT_OFF);
  int*   offs = (int*)(ws + OFF_OFF);
  int*   cur  = (int*)(ws + CUR_OFF);
  float* dinv = (float*)(ws + DNV_OFF);
  int*   csr  = (int*)(ws + CSR_OFF);
  bf16*  h1   = (bf16*)(ws + H1_OFF);
  float* hx2  = (float*)(ws + HX2_OFF);
  float* ru   = (float*)(ws + RU_OFF);
  bf16*  h2   = (bf16*)(ws + H2_OFF);
  float* yp   = (float*)(ws + YP_OFF);

  k_zero_i<<<dim3(32), dim3(256), 0, stream>>>(cnt, NNODES);
  k_prep_wctf<<<dim3((KT32 * 12 * 64 + 255) / 256), dim3(256), 0, stream>>>(W1, W2, wctf);
  k_hist<<<dim3((E + 255) / 256), dim3(256), 0, stream>>>(ei, E, cnt);
  k_scan<<<dim3(1), dim3(256), 0, stream>>>(cnt, offs, cur, dinv);
  k_fill<<<dim3((E + 255) / 256), dim3(256), 0, stream>>>(ei, E, cur, csr);
  if (ksplit == 1) {
    k_gemm<<<dim3(NNODES / BMB, 1), dim3(256), 0, stream>>>(x, hid, wctf, nullptr, h1, hx2, tpc);
  } else {
    k_gemm<<<dim3(NNODES / BMB, ksplit), dim3(256), 0, stream>>>(x, hid, wctf, yp, nullptr, nullptr, tpc);
    k_reduce<<<dim3(NNODES * NCOL / 256), dim3(256), 0, stream>>>(yp, h1, hx2, ksplit);
  }
  k_scat1<<<dim3(NNODES / 4), dim3(256), 0, stream>>>(h1, offs, csr, dinv, b1, ru);
  k_rh<<<dim3(NNODES / 4), dim3(256), 0, stream>>>(ru, hid, hx2, W2, h2);
  k_scat2<<<dim3(NNODES / 4), dim3(256), 0, stream>>>(h2, offs, csr, dinv, b2, ru, hid, out);
}

// Round 8
// 212.002 us; speedup vs baseline: 1.4068x; 1.0011x over previous
//
#include <hip/hip_runtime.h>
#include <hip/hip_bf16.h>
#include <stdint.h>

typedef __bf16 bf16x8 __attribute__((ext_vector_type(8)));
typedef float  f32x4  __attribute__((ext_vector_type(4)));
using bf16 = __hip_bfloat16;

#define NNODES 8192
#define FIN    8256      // 8192 + 64
#define NCOL   192       // 128 (W1) + 64 (W2 top)
#define KT32   258       // 8256 / 32
#define BMB    128       // rows per block (4 waves x 32 rows)

// ---- workspace layout (bytes) ----
enum : size_t {
  WCT_OFF  = 0,            // bf16 wctf [258][12][64][8]  3,170,304
  CNT_OFF  = 3170304,      // int  [8192]
  OFF_OFF  = 3203072,      // int  [8193]
  CUR_OFF  = 3236096,      // int  [8192]
  DNV_OFF  = 3268864,      // f32  [8192]
  CSR_OFF  = 3301632,      // int  [262144]
  H1_OFF   = 4350208,      // bf16 [8192][128]
  HX2_OFF  = 8544512,      // f32  [8192][64]
  RU_OFF   = 10641664,     // f32  [8192][128]
  H2_OFF   = 14835968,     // bf16 [8192][64]
  YP_OFF   = 16933120,     // f32  [ksplit][8192][192]
  YP_SLICE = 6291456
};

__global__ void k_zero_i(int* p, int n) {
  int i = blockIdx.x * 256 + threadIdx.x;
  if (i < n) p[i] = 0;
}

__global__ void k_out_zero(float* out) {
  int i = blockIdx.x * 256 + threadIdx.x;
  if (i < NNODES * 64) out[i] = 0.f;   // diagnostic signature if ws too small
}

// Build B in MFMA-fragment order: wctf[((t*12+nf)*64+lane)*8+j] =
//   Wc[k = t*32 + (lane>>4)*8 + j][col = nf*16 + (lane&15)]
__global__ void k_prep_wctf(const float* __restrict__ W1, const float* __restrict__ W2,
                            bf16* __restrict__ wctf) {
  int gid = blockIdx.x * 256 + threadIdx.x;
  if (gid >= KT32 * 12 * 64) return;
  int t = gid / 768;
  int rem = gid - t * 768;
  int nf = rem >> 6, lane = rem & 63;
  int col = nf * 16 + (lane & 15);
  int k0 = t * 32 + (lane >> 4) * 8;
  union { bf16 h[8]; uint4 v; } u;
#pragma unroll
  for (int j = 0; j < 8; ++j) {
    int k = k0 + j;
    float v;
    if (col < 128)      v = W1[(size_t)k * 128 + col];
    else if (k < 8192)  v = W2[(size_t)k * 64 + (col - 128)];
    else                v = 0.f;
    u.h[j] = __float2bfloat16(v);
  }
  *(uint4*)(wctf + (size_t)gid * 8) = u.v;
}

__global__ void k_hist(const int* __restrict__ ei, int E, int* cnt) {
  int e = blockIdx.x * 256 + threadIdx.x;
  if (e < E) atomicAdd(&cnt[ei[E + e]], 1);
}

__global__ void k_scan(const int* __restrict__ cnt, int* __restrict__ offs,
                       int* __restrict__ cur, float* __restrict__ dinv) {
  __shared__ int part[256];
  int tid = threadIdx.x;
  int base = tid * 32;
  int s = 0;
#pragma unroll
  for (int j = 0; j < 32; j++) s += cnt[base + j];
  part[tid] = s;
  __syncthreads();
  for (int off = 1; off < 256; off <<= 1) {
    int a = (tid >= off) ? part[tid - off] : 0;
    __syncthreads();
    part[tid] += a;
    __syncthreads();
  }
  int run = (tid == 0) ? 0 : part[tid - 1];
  for (int j = 0; j < 32; j++) {
    int c = cnt[base + j];
    offs[base + j] = run;
    cur[base + j]  = run;
    dinv[base + j] = rsqrtf((float)(c + 1));
    run += c;
  }
  if (tid == 255) offs[NNODES] = run;
}

__global__ void k_fill(const int* __restrict__ ei, int E, int* cur, int* __restrict__ csr) {
  int e = blockIdx.x * 256 + threadIdx.x;
  if (e < E) {
    int d = ei[E + e];
    int p = atomicAdd(&cur[d], 1);
    csr[p] = ei[e];
  }
}

__device__ __forceinline__ bf16x8 pack8(float4 a, float4 b) {
  union { bf16 h[8]; bf16x8 v; } u;
  u.h[0] = __float2bfloat16(a.x); u.h[1] = __float2bfloat16(a.y);
  u.h[2] = __float2bfloat16(a.z); u.h[3] = __float2bfloat16(a.w);
  u.h[4] = __float2bfloat16(b.x); u.h[5] = __float2bfloat16(b.y);
  u.h[6] = __float2bfloat16(b.z); u.h[7] = __float2bfloat16(b.w);
  return u.v;
}

__device__ __forceinline__ void gld16(void* ldsdst, const void* gsrc) {
  __builtin_amdgcn_global_load_lds(
      (__attribute__((address_space(1))) void*)gsrc,
      (__attribute__((address_space(3))) void*)ldsdst, 16, 0, 0);
}

// C = [x | hidden] @ Wc : M=8192, N=192, K=8256
// Same staging/layout as round 7 (verified), but counted-vmcnt pipeline (T4):
// STAGE(t+1) issued, then s_waitcnt vmcnt(7) (waits only stage(t)), raw s_barrier,
// ds_read+MFMA, raw s_barrier. Next-tile loads stay in flight across barriers.
__global__ __launch_bounds__(256, 2) void k_gemm(const float* __restrict__ x,
                                                 const float* __restrict__ hid,
                                                 const bf16* __restrict__ wctf,
                                                 float* __restrict__ yp,
                                                 bf16* __restrict__ h1d,
                                                 float* __restrict__ hx2d,
                                                 int tpc) {
  __shared__ uint4 smA[2][1024];   // 2 x 16 KB fp32 A tile [128 rows][8 slots of 16B]
  __shared__ uint4 smB[2][768];    // 2 x 12 KB bf16 B tile (fragment-packed)
  const int tid = threadIdx.x;
  const int lane = tid & 63, w = tid >> 6;
  const int rl = lane & 15, g = lane >> 4;
  const int m0 = blockIdx.x * BMB;
  const int chunk = blockIdx.y;
  const int t_lo = chunk * tpc;
  const int t_hi = (t_lo + tpc > KT32) ? KT32 : (t_lo + tpc);
  const int nt = t_hi - t_lo;

  // A staging sources (pre-swizzled): unit u = q*256+tid -> row=u>>3, slot s=u&7
  const float* asx[4]; const float* ash[4];
#pragma unroll
  for (int q = 0; q < 4; ++q) {
    int u = q * 256 + tid, row = u >> 3, s = u & 7;
    int sel = (s ^ (row & 7)) << 2;     // fp32 element offset within 32-elem tile
    asx[q] = x + (size_t)(m0 + row) * 8192 + sel;
    ash[q] = hid + (size_t)(m0 + row) * 64 + sel;
  }

  f32x4 acc0[12] = {};
  f32x4 acc1[12] = {};

  // fragment read slot indices (XOR involution matches staging pre-swizzle)
  const int sl0 = (g * 2) ^ (rl & 7);
  const int sl1 = (g * 2 + 1) ^ (rl & 7);
  const int ra0 = (w * 32 + rl) * 8;
  const int ra1 = (w * 32 + 16 + rl) * 8;

#define STAGE(b, t) do {                                                        \
    const int _t = (t);                                                         \
    if (_t < 256) {                                                             \
      const int _k = _t * 32;                                                   \
      _Pragma("unroll")                                                         \
      for (int q = 0; q < 4; ++q) gld16(&smA[b][q * 256 + tid], asx[q] + _k);   \
    } else {                                                                    \
      const int _k = (_t - 256) * 32;                                           \
      _Pragma("unroll")                                                         \
      for (int q = 0; q < 4; ++q) gld16(&smA[b][q * 256 + tid], ash[q] + _k);   \
    }                                                                           \
    const bf16* _bt = wctf + (size_t)_t * 6144;                                 \
    _Pragma("unroll")                                                           \
    for (int q = 0; q < 3; ++q)                                                 \
      gld16(&smB[b][q * 256 + tid], _bt + (size_t)(q * 256 + tid) * 8);         \
  } while (0)

  STAGE(0, t_lo);

  for (int it = 0; it < nt; ++it) {
    const int c = it & 1;
    const bool hn = (it + 1 < nt);
    if (hn) STAGE(c ^ 1, t_lo + it + 1);   // 7 loads into the other buffer

    // wait only for stage(it)'s loads (the 7 just issued stay in flight)
    if (hn) asm volatile("s_waitcnt vmcnt(7)" ::: "memory");
    else    asm volatile("s_waitcnt vmcnt(0)" ::: "memory");
    __builtin_amdgcn_s_barrier();          // all waves: LDS[c] fully written
    asm volatile("" ::: "memory");

    union { uint4 u; float4 f; } a00, a01, a10, a11;
    a00.u = smA[c][ra0 + sl0]; a01.u = smA[c][ra0 + sl1];
    a10.u = smA[c][ra1 + sl0]; a11.u = smA[c][ra1 + sl1];
    bf16x8 af0 = pack8(a00.f, a01.f);
    bf16x8 af1 = pack8(a10.f, a11.f);
#pragma unroll
    for (int nf = 0; nf < 12; ++nf) {
      bf16x8 bfr = *(const bf16x8*)&smB[c][nf * 64 + lane];
      acc0[nf] = __builtin_amdgcn_mfma_f32_16x16x32_bf16(af0, bfr, acc0[nf], 0, 0, 0);
      acc1[nf] = __builtin_amdgcn_mfma_f32_16x16x32_bf16(af1, bfr, acc1[nf], 0, 0, 0);
    }
    asm volatile("" ::: "memory");
    __builtin_amdgcn_s_barrier();          // readers done before next overwrite
    asm volatile("" ::: "memory");
  }
#undef STAGE

  // C/D layout (HW-verified): col = lane&15, row = (lane>>4)*4 + reg
  if (h1d) {  // direct mode (ksplit==1)
#pragma unroll
    for (int nf = 0; nf < 12; ++nf) {
      int col = nf * 16 + rl;
#pragma unroll
      for (int tt = 0; tt < 4; ++tt) {
        int ra = m0 + w * 32 + g * 4 + tt;
        int rb = ra + 16;
        if (col < 128) {
          h1d[(size_t)ra * 128 + col] = __float2bfloat16(acc0[nf][tt]);
          h1d[(size_t)rb * 128 + col] = __float2bfloat16(acc1[nf][tt]);
        } else {
          hx2d[(size_t)ra * 64 + (col - 128)] = acc0[nf][tt];
          hx2d[(size_t)rb * 64 + (col - 128)] = acc1[nf][tt];
        }
      }
    }
  } else {
    float* ypc = yp + (size_t)chunk * ((size_t)NNODES * NCOL);
#pragma unroll
    for (int nf = 0; nf < 12; ++nf) {
      int col = nf * 16 + rl;
#pragma unroll
      for (int tt = 0; tt < 4; ++tt) {
        int ra = m0 + w * 32 + g * 4 + tt;
        ypc[(size_t)ra * NCOL + col] = acc0[nf][tt];
        ypc[(size_t)(ra + 16) * NCOL + col] = acc1[nf][tt];
      }
    }
  }
}

// sum K-split partials; h1 -> bf16, hx2 -> fp32
__global__ void k_reduce(const float* __restrict__ yp, bf16* __restrict__ h1,
                         float* __restrict__ hx2, int nch) {
  int idx = blockIdx.x * 256 + threadIdx.x;  // < 8192*192
  float s = 0.f;
  for (int c = 0; c < nch; c++) s += yp[(size_t)c * ((size_t)NNODES * NCOL) + idx];
  int i = idx / NCOL, c = idx - i * NCOL;
  if (c < 128) h1[(size_t)i * 128 + c] = __float2bfloat16(s);
  else         hx2[(size_t)i * 64 + (c - 128)] = s;
}

__device__ __forceinline__ float bflo(unsigned v) { return __uint_as_float(v << 16); }
__device__ __forceinline__ float bfhi(unsigned v) { return __uint_as_float(v & 0xffff0000u); }

// one wave per node: ru = sigmoid(selfloop + sum_edges h1[src]*dinv[src]*dinv[dst] + b1)
__global__ void k_scat1(const bf16* __restrict__ h1b, const int* __restrict__ offs,
                        const int* __restrict__ csr, const float* __restrict__ dinv,
                        const float* __restrict__ b1, float* __restrict__ ru) {
  int node = blockIdx.x * 4 + (threadIdx.x >> 6);
  int lane = threadIdx.x & 63;
  const unsigned* h1u = (const unsigned*)h1b;   // 64 uints per row
  float dd = dinv[node];
  unsigned vv = h1u[(size_t)node * 64 + lane];
  float ax = bflo(vv) * dd * dd, ay = bfhi(vv) * dd * dd;
  int e0 = offs[node], e1 = offs[node + 1];
  for (int e = e0; e < e1; ++e) {
    int s = csr[e];
    float nrm = dinv[s] * dd;
    unsigned wv = h1u[(size_t)s * 64 + lane];
    ax += bflo(wv) * nrm;
    ay += bfhi(wv) * nrm;
  }
  ax += b1[lane * 2];
  ay += b1[lane * 2 + 1];
  ax = 1.f / (1.f + expf(-ax));
  ay = 1.f / (1.f + expf(-ay));
  ru[(size_t)node * 128 + lane * 2]     = ax;
  ru[(size_t)node * 128 + lane * 2 + 1] = ay;
}

// h2[i] = hx2[i] + (r[i] .* hidden[i]) @ W2_bottom  (r via the flat-reshape quirk)
__global__ void k_rh(const float* __restrict__ ru, const float* __restrict__ hidden,
                     const float* __restrict__ hx2, const float* __restrict__ W2,
                     bf16* __restrict__ h2) {
  __shared__ float W2s[64][64];
  __shared__ float rhs[4][64];
  int tid = threadIdx.x;
#pragma unroll
  for (int t = 0; t < 16; ++t) {
    int idx = tid + 256 * t;  // 4096
    int j = idx >> 6, c = idx & 63;
    W2s[j][c] = W2[(size_t)(8192 + j) * 64 + c];
  }
  int w = tid >> 6, lane = tid & 63;
  int i = blockIdx.x * 4 + w;
  float rv = ru[(size_t)(i >> 1) * 128 + ((i & 1) << 6) + lane];
  float hv = hidden[(size_t)i * 64 + lane];
  rhs[w][lane] = rv * hv;
  __syncthreads();
  float acc = hx2[(size_t)i * 64 + lane];
#pragma unroll 8
  for (int j = 0; j < 64; ++j) acc += rhs[w][j] * W2s[j][lane];
  h2[(size_t)i * 64 + lane] = __float2bfloat16(acc);
}

// one wave per node: c = tanh(gather(h2)+b2); out = u*h + (1-u)*c  (u via reshape quirk)
__global__ void k_scat2(const bf16* __restrict__ h2b, const int* __restrict__ offs,
                        const int* __restrict__ csr, const float* __restrict__ dinv,
                        const float* __restrict__ b2, const float* __restrict__ ru,
                        const float* __restrict__ hidden, float* __restrict__ out) {
  int node = blockIdx.x * 4 + (threadIdx.x >> 6);
  int lane = threadIdx.x & 63;
  const unsigned short* h2u = (const unsigned short*)h2b;
  float dd = dinv[node];
  float acc = bflo((unsigned)h2u[(size_t)node * 64 + lane]) * dd * dd;
  int e0 = offs[node], e1 = offs[node + 1];
  for (int e = e0; e < e1; ++e) {
    int s = csr[e];
    acc += bflo((unsigned)h2u[(size_t)s * 64 + lane]) * dinv[s] * dd;
  }
  acc += b2[lane];
  float cv = tanhf(acc);
  float u = ru[(size_t)(4096 + (node >> 1)) * 128 + ((node & 1) << 6) + lane];
  float hv = hidden[(size_t)node * 64 + lane];
  out[(size_t)node * 64 + lane] = u * hv + (1.f - u) * cv;
}

extern "C" void kernel_launch(void* const* d_in, const int* in_sizes, int n_in,
                              void* d_out, int out_size, void* d_ws, size_t ws_size,
                              hipStream_t stream) {
  (void)n_in; (void)out_size;
  const float* x   = (const float*)d_in[0];
  const float* hid = (const float*)d_in[1];
  const float* W1  = (const float*)d_in[2];
  const float* b1  = (const float*)d_in[3];
  const float* W2  = (const float*)d_in[4];
  const float* b2  = (const float*)d_in[5];
  const int*   ei  = (const int*)d_in[6];
  const int E = in_sizes[6] / 2;
  float* out = (float*)d_out;

  int ksplit;
  if      (ws_size >= YP_OFF + 8ull * YP_SLICE) ksplit = 8;
  else if (ws_size >= YP_OFF + 4ull * YP_SLICE) ksplit = 4;
  else if (ws_size >= YP_OFF + 2ull * YP_SLICE) ksplit = 2;
  else if (ws_size >= YP_OFF)                   ksplit = 1;   // direct mode
  else {
    k_out_zero<<<dim3(NNODES * 64 / 256), dim3(256), 0, stream>>>(out);
    return;
  }
  const int tpc = (KT32 + ksplit - 1) / ksplit;

  char* ws = (char*)d_ws;
  bf16*  wctf = (bf16*)(ws + WCT_OFF);
  int*   cnt  = (int*)(ws + CNT_OFF);
  int*   offs = (int*)(ws + OFF_OFF);
  int*   cur  = (int*)(ws + CUR_OFF);
  float* dinv = (float*)(ws + DNV_OFF);
  int*   csr  = (int*)(ws + CSR_OFF);
  bf16*  h1   = (bf16*)(ws + H1_OFF);
  float* hx2  = (float*)(ws + HX2_OFF);
  float* ru   = (float*)(ws + RU_OFF);
  bf16*  h2   = (bf16*)(ws + H2_OFF);
  float* yp   = (float*)(ws + YP_OFF);

  k_zero_i<<<dim3(32), dim3(256), 0, stream>>>(cnt, NNODES);
  k_prep_wctf<<<dim3((KT32 * 12 * 64 + 255) / 256), dim3(256), 0, stream>>>(W1, W2, wctf);
  k_hist<<<dim3((E + 255) / 256), dim3(256), 0, stream>>>(ei, E, cnt);
  k_scan<<<dim3(1), dim3(256), 0, stream>>>(cnt, offs, cur, dinv);
  k_fill<<<dim3((E + 255) / 256), dim3(256), 0, stream>>>(ei, E, cur, csr);
  if (ksplit == 1) {
    k_gemm<<<dim3(NNODES / BMB, 1), dim3(256), 0, stream>>>(x, hid, wctf, nullptr, h1, hx2, tpc);
  } else {
    k_gemm<<<dim3(NNODES / BMB, ksplit), dim3(256), 0, stream>>>(x, hid, wctf, yp, nullptr, nullptr, tpc);
    k_reduce<<<dim3(NNODES * NCOL / 256), dim3(256), 0, stream>>>(yp, h1, hx2, ksplit);
  }
  k_scat1<<<dim3(NNODES / 4), dim3(256), 0, stream>>>(h1, offs, csr, dinv, b1, ru);
  k_rh<<<dim3(NNODES / 4), dim3(256), 0, stream>>>(ru, hid, hx2, W2, h2);
  k_scat2<<<dim3(NNODES / 4), dim3(256), 0, stream>>>(h2, offs, csr, dinv, b2, ru, hid, out);
}